// Round 6
// baseline (786.204 us; speedup 1.0000x reference)
//
#include <hip/hip_runtime.h>
#include <stdint.h>

// y[m,o] = sum_k x[m,k]*(W8[o,k]-zero[o])*scale[o] + bias[o], M=8192 N=11008 K=4096.
// x ~= xs_m*(128*h + l) (h,l int8); G = xs_m*(128*Gh + Gl) via two i8 MFMA GEMMs
// sharing B-frags; y = scale*G - scale*zero*rowsum + bias.
// R6: mfma_i32_32x32x32_i8 (11% faster/op), K-step=32 software pipeline:
// step k+1's 6 ds_read_b128 issue before step k's 8-MFMA cluster (2 frag sets,
// 48 VGPR), ONE lgkmcnt(0)+vmcnt(0)+s_barrier per tile, last MFMA cluster after
// the barrier (runs from regs, overlaps other waves' next-tile reads).
// T2 XOR swizzle (slot ^= row&7) via inverse-swizzled global source.

#define M_DIM 8192
#define N_DIM 11008
#define K_DIM 4096
#define NT    (K_DIM / 128)   // 32 K-tiles
#define BUFB  65536           // bytes per LDS buffer: Ah 16K | Al 16K | B 32K

typedef __attribute__((ext_vector_type(4))) int i32x4;
typedef __attribute__((ext_vector_type(16))) int i32x16;

// ---------------- prep kernels ----------------

__global__ void convert_w_kernel(const int* __restrict__ w,
                                 int8_t* __restrict__ o, int n4) {
  int idx = blockIdx.x * blockDim.x + threadIdx.x;
  int stride = gridDim.x * blockDim.x;
  for (int i = idx; i < n4; i += stride) {
    int4 v = ((const int4*)w)[i];
    int r = (v.x & 255) | ((v.y & 255) << 8) | ((v.z & 255) << 16) | ((v.w & 255) << 24);
    ((int*)o)[i] = r;
  }
}

__global__ __launch_bounds__(256) void quantx_kernel(
    const float* __restrict__ x, int8_t* __restrict__ h8, int8_t* __restrict__ l8,
    float* __restrict__ xs, float* __restrict__ rsum) {
  const int row = blockIdx.x;
  const int t = threadIdx.x;
  const float4* px = (const float4*)(x + (size_t)row * K_DIM);
  float4 v[4];
  float mx = 0.f, sm = 0.f;
  #pragma unroll
  for (int i = 0; i < 4; ++i) {
    v[i] = px[i * 256 + t];
    mx = fmaxf(mx, fmaxf(fmaxf(fabsf(v[i].x), fabsf(v[i].y)),
                         fmaxf(fabsf(v[i].z), fabsf(v[i].w))));
    sm += v[i].x + v[i].y + v[i].z + v[i].w;
  }
  #pragma unroll
  for (int off = 32; off > 0; off >>= 1) {
    mx = fmaxf(mx, __shfl_down(mx, off));
    sm += __shfl_down(sm, off);
  }
  __shared__ float rmx[4], rsm[4];
  const int wv = t >> 6, ln = t & 63;
  if (ln == 0) { rmx[wv] = mx; rsm[wv] = sm; }
  __syncthreads();
  const float rowmax = fmaxf(fmaxf(rmx[0], rmx[1]), fmaxf(rmx[2], rmx[3]));
  if (t == 0) {
    xs[row] = rowmax > 0.f ? rowmax / 16256.f : 0.f;
    rsum[row] = rsm[0] + rsm[1] + rsm[2] + rsm[3];
  }
  const float inv = rowmax > 0.f ? 16256.f / rowmax : 0.f;
  int* hp = (int*)(h8 + (size_t)row * K_DIM);
  int* lp = (int*)(l8 + (size_t)row * K_DIM);
  #pragma unroll
  for (int i = 0; i < 4; ++i) {
    int q0 = (int)rintf(v[i].x * inv);
    int q1 = (int)rintf(v[i].y * inv);
    int q2 = (int)rintf(v[i].z * inv);
    int q3 = (int)rintf(v[i].w * inv);
    int h0 = (q0 + 64) >> 7, h1 = (q1 + 64) >> 7, h2 = (q2 + 64) >> 7, h3 = (q3 + 64) >> 7;
    int l0 = q0 - (h0 << 7), l1 = q1 - (h1 << 7), l2 = q2 - (h2 << 7), l3 = q3 - (h3 << 7);
    hp[i * 256 + t] = (h0 & 255) | ((h1 & 255) << 8) | ((h2 & 255) << 16) | ((h3 & 255) << 24);
    lp[i * 256 + t] = (l0 & 255) | ((l1 & 255) << 8) | ((l2 & 255) << 16) | ((l3 & 255) << 24);
  }
}

// ---------------- main GEMM ----------------

__device__ __forceinline__ void stage_A(
    const int8_t* __restrict__ Ah, const int8_t* __restrict__ Al,
    size_t a_base, int ks, int srow, int scol, int wave, int8_t* buf) {
  #pragma unroll
  for (int r = 0; r < 2; ++r) {
    const int8_t* g = Ah + a_base + (size_t)(r * 64 + srow) * K_DIM + ks + scol;
    __builtin_amdgcn_global_load_lds((const __attribute__((address_space(1))) void*)g,
        (__attribute__((address_space(3))) void*)(buf + r * 8192 + wave * 1024), 16, 0, 0);
  }
  #pragma unroll
  for (int r = 0; r < 2; ++r) {
    const int8_t* g = Al + a_base + (size_t)(r * 64 + srow) * K_DIM + ks + scol;
    __builtin_amdgcn_global_load_lds((const __attribute__((address_space(1))) void*)g,
        (__attribute__((address_space(3))) void*)(buf + 16384 + r * 8192 + wave * 1024), 16, 0, 0);
  }
}

__device__ __forceinline__ void stage_B(
    const int8_t* __restrict__ Bw, size_t b_base,
    int ks, int srow, int scol, int wave, int8_t* buf) {
  #pragma unroll
  for (int r = 0; r < 4; ++r) {
    const int8_t* g = Bw + b_base + (size_t)(r * 64 + srow) * K_DIM + ks + scol;
    __builtin_amdgcn_global_load_lds((const __attribute__((address_space(1))) void*)g,
        (__attribute__((address_space(3))) void*)(buf + 32768 + r * 8192 + wave * 1024), 16, 0, 0);
  }
}

__global__ __launch_bounds__(512, 2) void qgemm_kernel(
    const int8_t* __restrict__ Ah, const int8_t* __restrict__ Al,
    const int8_t* __restrict__ Bw, const float* __restrict__ xs,
    const float* __restrict__ rowsum, const float* __restrict__ scale,
    const float* __restrict__ zero, const float* __restrict__ bias,
    float* __restrict__ out) {
  extern __shared__ int8_t smem[];  // 2 x 64KB

  const int tid = threadIdx.x;
  const int wave = tid >> 6;
  const int lane = tid & 63;

  // XCD-chunked + grouped mapping: nwg=2752=8*344; each XCD gets an 8-bm strip.
  const int bid = blockIdx.x;
  const int wg = (bid & 7) * 344 + (bid >> 3);
  const int group = wg / 344;
  const int rem = wg % 344;
  const int bm = group * 8 + (rem & 7);  // 0..63 (M/128)
  const int bn = rem >> 3;               // 0..42 (N/256)

  const int wr = wave >> 2;  // 0..1: 64-row half of 128
  const int wc = wave & 3;   // 0..3: 64-col quarter of 256

  i32x16 acch[2][2], accl[2][2];
  #pragma unroll
  for (int i = 0; i < 2; ++i)
    #pragma unroll
    for (int j = 0; j < 2; ++j) {
      acch[i][j] = (i32x16)(0);
      accl[i][j] = (i32x16)(0);
    }

  // staging addressing: thread owns phys slot (tid&7) of row (tid>>3); load
  // global slot (tid&7)^(row&7) so phys = logical ^ (row&7).
  const int srow = tid >> 3;                               // 0..63
  const int scol = (((tid & 7) ^ ((tid >> 3) & 7)) << 4);  // byte offset in 128B row
  const size_t a_base = (size_t)(bm * 128) * K_DIM;
  const size_t b_base = (size_t)((size_t)bn * 256) * K_DIM;

  // 32x32x32 i8 fragment addressing: lane holds row (lane&31), 16B K-chunk
  // (lane>>5) of each K=32 step s. logical slot = 2s + (lane>>5);
  // phys slot = slot ^ (row&7), row&7 == lane&7 for all fragment rows.
  const int r31 = lane & 31;
  const int g5 = lane >> 5;
  const int sw = lane & 7;
  int scb[4];
  #pragma unroll
  for (int s = 0; s < 4; ++s) scb[s] = (((2 * s + g5) ^ sw) << 4);

  const int arow0 = (wr * 64 + r31) * 128;       // A row bytes, mi=0
  const int arow1 = arow0 + 32 * 128;            // mi=1
  const int brow0 = (wc * 64 + r31) * 128;       // B row bytes, ni=0
  const int brow1 = brow0 + 32 * 128;            // ni=1

#define RD_STEP(s, fa, fb) do {                                         \
    fb[0]    = *(const i32x4*)(ldsB_  + brow0 + scb[s]);                \
    fb[1]    = *(const i32x4*)(ldsB_  + brow1 + scb[s]);                \
    fa[0][0] = *(const i32x4*)(ldsAh_ + arow0 + scb[s]);                \
    fa[0][1] = *(const i32x4*)(ldsAl_ + arow0 + scb[s]);                \
    fa[1][0] = *(const i32x4*)(ldsAh_ + arow1 + scb[s]);                \
    fa[1][1] = *(const i32x4*)(ldsAl_ + arow1 + scb[s]);                \
  } while (0)

#define MM_STEP(fa, fb) do {                                                        \
    __builtin_amdgcn_s_setprio(1);                                                  \
    acch[0][0] = __builtin_amdgcn_mfma_i32_32x32x32_i8(fa[0][0], fb[0], acch[0][0], 0, 0, 0); \
    accl[0][0] = __builtin_amdgcn_mfma_i32_32x32x32_i8(fa[0][1], fb[0], accl[0][0], 0, 0, 0); \
    acch[0][1] = __builtin_amdgcn_mfma_i32_32x32x32_i8(fa[0][0], fb[1], acch[0][1], 0, 0, 0); \
    accl[0][1] = __builtin_amdgcn_mfma_i32_32x32x32_i8(fa[0][1], fb[1], accl[0][1], 0, 0, 0); \
    acch[1][0] = __builtin_amdgcn_mfma_i32_32x32x32_i8(fa[1][0], fb[0], acch[1][0], 0, 0, 0); \
    accl[1][0] = __builtin_amdgcn_mfma_i32_32x32x32_i8(fa[1][1], fb[0], accl[1][0], 0, 0, 0); \
    acch[1][1] = __builtin_amdgcn_mfma_i32_32x32x32_i8(fa[1][0], fb[1], acch[1][1], 0, 0, 0); \
    accl[1][1] = __builtin_amdgcn_mfma_i32_32x32x32_i8(fa[1][1], fb[1], accl[1][1], 0, 0, 0); \
    __builtin_amdgcn_s_setprio(0);                                                  \
  } while (0)

  // prologue: stage tile 0, drain, barrier
  stage_A(Ah, Al, a_base, 0, srow, scol, wave, smem);
  stage_B(Bw, b_base, 0, srow, scol, wave, smem);
  asm volatile("s_waitcnt vmcnt(0)" ::: "memory");
  __builtin_amdgcn_s_barrier();

  i32x4 fa0[2][2], fb0[2], fa1[2][2], fb1[2];

  for (int t = 0; t < NT; ++t) {
    const int8_t* buf = smem + (t & 1) * BUFB;
    int8_t* nxt = smem + ((t + 1) & 1) * BUFB;
    const int8_t* ldsAh_ = buf;
    const int8_t* ldsAl_ = buf + 16384;
    const int8_t* ldsB_  = buf + 32768;
    const bool pf = (t + 1 < NT);
    const int nks = (t + 1) * 128;

    RD_STEP(0, fa0, fb0);
    if (pf) stage_A(Ah, Al, a_base, nks, srow, scol, wave, nxt);
    RD_STEP(1, fa1, fb1);
    if (pf) stage_B(Bw, b_base, nks, srow, scol, wave, nxt);

    MM_STEP(fa0, fb0);        // step 0 (reads for step 1 already in flight)
    RD_STEP(2, fa0, fb0);
    MM_STEP(fa1, fb1);        // step 1
    RD_STEP(3, fa1, fb1);
    MM_STEP(fa0, fb0);        // step 2

    // all tile-t ds_reads landed (step-3 issued one MFMA cluster ago) so the
    // next tile's staging can't clobber unread bytes; t+1 loads also landed.
    asm volatile("s_waitcnt lgkmcnt(0)" ::: "memory");
    asm volatile("s_waitcnt vmcnt(0)" ::: "memory");
    __builtin_amdgcn_s_barrier();

    MM_STEP(fa1, fb1);        // step 3, from regs — overlaps next-tile reads
  }

  // epilogue: G = xs_m*(128*Gh + Gl); y = scale*G - scale*zero*rowsum + bias
  // C/D 32x32 layout: col = lane&31, row = (reg&3) + 8*(reg>>2) + 4*(lane>>5)
  const int row0 = bm * 128 + wr * 64;
  const int col0 = bn * 256 + wc * 64;
  float s_[2], sz_[2], b_[2];
  #pragma unroll
  for (int ni = 0; ni < 2; ++ni) {
    const int n = col0 + ni * 32 + r31;
    const float s = scale[n];
    s_[ni] = s;
    sz_[ni] = s * zero[n];
    b_[ni] = bias[n];
  }
  #pragma unroll
  for (int mi = 0; mi < 2; ++mi) {
    #pragma unroll
    for (int j = 0; j < 16; ++j) {
      const int m = row0 + mi * 32 + (j & 3) + 8 * (j >> 2) + 4 * g5;
      const float xsm = xs[m];
      const float rs = rowsum[m];
      float* po = out + (size_t)m * N_DIM + col0 + r31;
      #pragma unroll
      for (int ni = 0; ni < 2; ++ni) {
        const float G = xsm * (128.f * (float)acch[mi][ni][j] + (float)accl[mi][ni][j]);
        po[ni * 32] = s_[ni] * G - sz_[ni] * rs + b_[ni];
      }
    }
  }
}

// ---------------- fallback (only if workspace too small) ----------------

__global__ void fallback_kernel(const float* __restrict__ x, const int* __restrict__ w,
                                const float* __restrict__ scale, const float* __restrict__ zero,
                                const float* __restrict__ bias, float* __restrict__ out) {
  const int n = blockIdx.x * 16 + (threadIdx.x & 15);
  const int m = blockIdx.y * 16 + (threadIdx.x >> 4);
  const float z = zero[n];
  const float* xr = x + (size_t)m * K_DIM;
  const int* wr = w + (size_t)n * K_DIM;
  float acc = 0.f;
  for (int k = 0; k < K_DIM; ++k) acc += xr[k] * ((float)wr[k] - z);
  out[(size_t)m * N_DIM + n] = scale[n] * acc + bias[n];
}

// ---------------- launch ----------------

extern "C" void kernel_launch(void* const* d_in, const int* in_sizes, int n_in,
                              void* d_out, int out_size, void* d_ws, size_t ws_size,
                              hipStream_t stream) {
  const float* x     = (const float*)d_in[0];
  const int*   w     = (const int*)d_in[1];
  const float* scale = (const float*)d_in[2];
  const float* zero  = (const float*)d_in[3];
  const float* bias  = (const float*)d_in[4];
  float* out = (float*)d_out;

  const size_t n_x = (size_t)M_DIM * K_DIM;
  const size_t n_w = (size_t)N_DIM * K_DIM;
  const size_t need = n_x * 2 + n_w + (size_t)M_DIM * 8;  // ~112 MB

  if (ws_size < need) {
    dim3 gr(N_DIM / 16, M_DIM / 16);
    fallback_kernel<<<gr, 256, 0, stream>>>(x, w, scale, zero, bias, out);
    return;
  }

  int8_t* x_h = (int8_t*)d_ws;
  int8_t* x_l = x_h + n_x;
  int8_t* w_8 = x_l + n_x;
  float* rsum = (float*)(w_8 + n_w);
  float* xs   = rsum + M_DIM;

  convert_w_kernel<<<2048, 256, 0, stream>>>(w, w_8, (int)(n_w / 4));
  quantx_kernel<<<M_DIM, 256, 0, stream>>>(x, x_h, x_l, xs, rsum);

  (void)hipFuncSetAttribute((const void*)qgemm_kernel,
                            hipFuncAttributeMaxDynamicSharedMemorySize, 2 * BUFB);

  const int nblocks = (M_DIM / 128) * (N_DIM / 256);  // 64 * 43 = 2752
  qgemm_kernel<<<nblocks, 512, 2 * BUFB, stream>>>(x_h, x_l, w_8, xs, rsum,
                                                   scale, zero, bias, out);
}